// Round 1
// baseline (269.140 us; speedup 1.0000x reference)
//
#include <hip/hip_runtime.h>
#include <hip/hip_bf16.h>

// out[b][o] = sum_i x[b][i] * W[o][i] + 2*bias[o]
// M = N = K = 4096, fp32 in / fp32 out.
// Round 1: bf16-MFMA GEMM, 128x128 tile, BK=32, reg-staged fp32->bf16 into LDS.

typedef short bf16x8 __attribute__((ext_vector_type(8)));
typedef short s16x4  __attribute__((ext_vector_type(4)));
typedef float f32x4  __attribute__((ext_vector_type(4)));

constexpr int MDIM = 4096, NDIM = 4096, KDIM = 4096;
constexpr int BM = 128, BN = 128, BK = 32;
constexpr int LDT = BK + 8;   // padded LDS row stride (elements): 80 B -> 2-way bank aliasing only

__device__ __forceinline__ short f2bf(float f) {
    __hip_bfloat16 h = __float2bfloat16(f);   // round-to-nearest-even
    short s;
    __builtin_memcpy(&s, &h, 2);
    return s;
}

__global__ __launch_bounds__(256)
void gemm_xwt_bias2(const float* __restrict__ X, const float* __restrict__ W,
                    const float* __restrict__ Bv, float* __restrict__ Out)
{
    __shared__ short As[BM * LDT];
    __shared__ short Bs[BN * LDT];

    const int tid  = threadIdx.x;
    const int lane = tid & 63;
    const int wid  = tid >> 6;          // 0..3
    const int wr   = wid >> 1;          // wave row in 2x2
    const int wc   = wid & 1;           // wave col in 2x2
    const int tm0  = blockIdx.y * BM;
    const int tn0  = blockIdx.x * BN;

    // staging: 256 threads cover 128 rows x 32 floats; thread -> (row, 4-float chunk)
    const int srow = tid >> 3;          // 0..31  (+32*i for i=0..3)
    const int scol = (tid & 7) * 4;     // 0,4,...,28

    // fragment indexing (m89-verified 16x16x32 layout)
    const int g   = lane >> 4;          // k-chunk group 0..3 ; also D-row group
    const int r16 = lane & 15;          // A/B row within fragment ; D col

    f32x4 acc[4][4] = {};

    const float* xg = X + (size_t)(tm0 + srow) * KDIM + scol;
    const float* wg = W + (size_t)(tn0 + srow) * KDIM + scol;

    for (int k0 = 0; k0 < KDIM; k0 += BK) {
        // ---- stage A,B tiles: global fp32 -> cvt bf16 -> LDS ----
        #pragma unroll
        for (int i = 0; i < 4; ++i) {
            const int row = srow + 32 * i;
            f32x4 av = *(const f32x4*)(xg + (size_t)(32 * i) * KDIM + k0);
            f32x4 bv = *(const f32x4*)(wg + (size_t)(32 * i) * KDIM + k0);
            s16x4 pa = { f2bf(av[0]), f2bf(av[1]), f2bf(av[2]), f2bf(av[3]) };
            s16x4 pb = { f2bf(bv[0]), f2bf(bv[1]), f2bf(bv[2]), f2bf(bv[3]) };
            *(s16x4*)&As[row * LDT + scol] = pa;
            *(s16x4*)&Bs[row * LDT + scol] = pb;
        }
        __syncthreads();

        // ---- LDS -> frags -> 16 MFMA ----
        bf16x8 af[4], bfr[4];
        #pragma unroll
        for (int mi = 0; mi < 4; ++mi)
            af[mi] = *(const bf16x8*)&As[(wr * 64 + mi * 16 + r16) * LDT + g * 8];
        #pragma unroll
        for (int ni = 0; ni < 4; ++ni)
            bfr[ni] = *(const bf16x8*)&Bs[(wc * 64 + ni * 16 + r16) * LDT + g * 8];
        #pragma unroll
        for (int mi = 0; mi < 4; ++mi) {
            #pragma unroll
            for (int ni = 0; ni < 4; ++ni)
                acc[mi][ni] = __builtin_amdgcn_mfma_f32_16x16x32_bf16(
                                  af[mi], bfr[ni], acc[mi][ni], 0, 0, 0);
        }
        __syncthreads();
    }

    // ---- epilogue: + 2*bias, fp32 store ----
    float bb[4];
    #pragma unroll
    for (int ni = 0; ni < 4; ++ni)
        bb[ni] = 2.0f * Bv[tn0 + wc * 64 + ni * 16 + r16];

    #pragma unroll
    for (int mi = 0; mi < 4; ++mi) {
        #pragma unroll
        for (int r = 0; r < 4; ++r) {
            const int row = tm0 + wr * 64 + mi * 16 + g * 4 + r;
            float* orow = Out + (size_t)row * NDIM + tn0 + wc * 64 + r16;
            #pragma unroll
            for (int ni = 0; ni < 4; ++ni)
                orow[ni * 16] = acc[mi][ni][r] + bb[ni];
        }
    }
}

extern "C" void kernel_launch(void* const* d_in, const int* in_sizes, int n_in,
                              void* d_out, int out_size, void* d_ws, size_t ws_size,
                              hipStream_t stream) {
    const float* X  = (const float*)d_in[0];   // [4096, 4096]
    const float* W  = (const float*)d_in[1];   // [4096, 4096]
    const float* Bv = (const float*)d_in[2];   // [4096]
    float* Out = (float*)d_out;

    dim3 grid(NDIM / BN, MDIM / BM);   // (32, 32)
    gemm_xwt_bias2<<<grid, 256, 0, stream>>>(X, W, Bv, Out);
}

// Round 2
// 212.345 us; speedup vs baseline: 1.2675x; 1.2675x over previous
//
#include <hip/hip_runtime.h>
#include <hip/hip_bf16.h>

// out[b][o] = sum_i x[b][i] * W[o][i] + 2*bias[o];  M=N=K=4096, fp32 in/out.
// Round 2: (1) fp32->bf16 pre-convert of X,W into d_ws (memory-bound pass),
//          (2) m97-structure GEMM: global_load_lds width-16, linear LDS [128][32],
//              2-barrier K-loop, 4 waves x 4x4 16x16x32 bf16 MFMA.
// Fallback to the R1 reg-staged kernel if ws_size < 67 MB.

typedef short bf16x8 __attribute__((ext_vector_type(8)));
typedef short s16x4  __attribute__((ext_vector_type(4)));
typedef short s16x8  __attribute__((ext_vector_type(8)));
typedef float f32x4  __attribute__((ext_vector_type(4)));

constexpr int MDIM = 4096, NDIM = 4096, KDIM = 4096;
constexpr int BM = 128, BN = 128, BK = 32;

__device__ __forceinline__ short f2bf(float f) {
    __hip_bfloat16 h = __float2bfloat16(f);   // RNE
    short s;
    __builtin_memcpy(&s, &h, 2);
    return s;
}

// ---------------- pass 1: fp32 -> bf16 convert ----------------
__global__ __launch_bounds__(256)
void cvt_f32_bf16(const float* __restrict__ in, short* __restrict__ out, int n8) {
    int idx    = blockIdx.x * blockDim.x + threadIdx.x;
    int stride = gridDim.x * blockDim.x;
    const f32x4* in4 = (const f32x4*)in;
    s16x8* out8 = (s16x8*)out;
    for (int i = idx; i < n8; i += stride) {
        f32x4 a = in4[2 * i];
        f32x4 b = in4[2 * i + 1];
        s16x8 o = { f2bf(a[0]), f2bf(a[1]), f2bf(a[2]), f2bf(a[3]),
                    f2bf(b[0]), f2bf(b[1]), f2bf(b[2]), f2bf(b[3]) };
        out8[i] = o;
    }
}

// ---------------- pass 2: bf16 GEMM, m97 structure ----------------
typedef const __attribute__((address_space(1))) void* gas_t;
typedef __attribute__((address_space(3))) void*       las_t;

__global__ __launch_bounds__(256)
void gemm_bf16_gll(const short* __restrict__ Xb, const short* __restrict__ Wb,
                   const float* __restrict__ Bv, float* __restrict__ Out)
{
    // linear layout REQUIRED for global_load_lds (wave-uniform base + lane*16)
    __shared__ short As[BM * BK];
    __shared__ short Bs[BN * BK];

    const int tid  = threadIdx.x;
    const int lane = tid & 63;
    const int wid  = tid >> 6;          // 0..3
    const int wr   = wid >> 1;          // wave row in 2x2
    const int wc   = wid & 1;           // wave col in 2x2
    const int tm0  = blockIdx.y * BM;
    const int tn0  = blockIdx.x * BN;

    // staging geometry: segment = 1024 B = 16 rows of [32] bf16.
    // wave w stages segments {2w, 2w+1} of each tile.
    // lane l -> row (l>>2) within segment, col (l&3)*8 bf16.
    const int lrow = lane >> 2;
    const int lcol = (lane & 3) * 8;

    // fragment indexing (m89-verified 16x16x32 layout)
    const int g   = lane >> 4;          // k-chunk group 0..3 ; also D-row group
    const int r16 = lane & 15;          // A/B row within fragment ; D col

    f32x4 acc[4][4] = {};

    const int s0 = 2 * wid, s1 = 2 * wid + 1;
    const short* xg0 = Xb + (size_t)(tm0 + s0 * 16 + lrow) * KDIM + lcol;
    const short* xg1 = Xb + (size_t)(tm0 + s1 * 16 + lrow) * KDIM + lcol;
    const short* wg0 = Wb + (size_t)(tn0 + s0 * 16 + lrow) * KDIM + lcol;
    const short* wg1 = Wb + (size_t)(tn0 + s1 * 16 + lrow) * KDIM + lcol;
    las_t la0 = (las_t)&As[s0 * 16 * BK];
    las_t la1 = (las_t)&As[s1 * 16 * BK];
    las_t lb0 = (las_t)&Bs[s0 * 16 * BK];
    las_t lb1 = (las_t)&Bs[s1 * 16 * BK];

    for (int k0 = 0; k0 < KDIM; k0 += BK) {
        // ---- stage A,B tiles: HBM/L3 -> LDS direct, 16 B per lane ----
        __builtin_amdgcn_global_load_lds((gas_t)(xg0 + k0), la0, 16, 0, 0);
        __builtin_amdgcn_global_load_lds((gas_t)(xg1 + k0), la1, 16, 0, 0);
        __builtin_amdgcn_global_load_lds((gas_t)(wg0 + k0), lb0, 16, 0, 0);
        __builtin_amdgcn_global_load_lds((gas_t)(wg1 + k0), lb1, 16, 0, 0);
        __syncthreads();   // compiler drains vmcnt before barrier -> data ready

        // ---- LDS -> frags -> 16 MFMA ----
        bf16x8 af[4], bfr[4];
        #pragma unroll
        for (int mi = 0; mi < 4; ++mi)
            af[mi] = *(const bf16x8*)&As[(wr * 64 + mi * 16 + r16) * BK + g * 8];
        #pragma unroll
        for (int ni = 0; ni < 4; ++ni)
            bfr[ni] = *(const bf16x8*)&Bs[(wc * 64 + ni * 16 + r16) * BK + g * 8];
        #pragma unroll
        for (int mi = 0; mi < 4; ++mi) {
            #pragma unroll
            for (int ni = 0; ni < 4; ++ni)
                acc[mi][ni] = __builtin_amdgcn_mfma_f32_16x16x32_bf16(
                                  af[mi], bfr[ni], acc[mi][ni], 0, 0, 0);
        }
        __syncthreads();   // before next iteration overwrites LDS
    }

    // ---- epilogue: + 2*bias, fp32 store ----
    float bb[4];
    #pragma unroll
    for (int ni = 0; ni < 4; ++ni)
        bb[ni] = 2.0f * Bv[tn0 + wc * 64 + ni * 16 + r16];

    #pragma unroll
    for (int mi = 0; mi < 4; ++mi) {
        #pragma unroll
        for (int r = 0; r < 4; ++r) {
            const int row = tm0 + wr * 64 + mi * 16 + g * 4 + r;
            float* orow = Out + (size_t)row * NDIM + tn0 + wc * 64 + r16;
            #pragma unroll
            for (int ni = 0; ni < 4; ++ni)
                orow[ni * 16] = acc[mi][ni][r] + bb[ni];
        }
    }
}

// ---------------- fallback (R1 kernel): fp32 reg-staged ----------------
constexpr int LDT = BK + 8;
__global__ __launch_bounds__(256)
void gemm_xwt_bias2(const float* __restrict__ X, const float* __restrict__ W,
                    const float* __restrict__ Bv, float* __restrict__ Out)
{
    __shared__ short As[BM * LDT];
    __shared__ short Bs[BN * LDT];
    const int tid  = threadIdx.x;
    const int lane = tid & 63;
    const int wid  = tid >> 6;
    const int wr   = wid >> 1;
    const int wc   = wid & 1;
    const int tm0  = blockIdx.y * BM;
    const int tn0  = blockIdx.x * BN;
    const int srow = tid >> 3;
    const int scol = (tid & 7) * 4;
    const int g   = lane >> 4;
    const int r16 = lane & 15;
    f32x4 acc[4][4] = {};
    const float* xg = X + (size_t)(tm0 + srow) * KDIM + scol;
    const float* wg = W + (size_t)(tn0 + srow) * KDIM + scol;
    for (int k0 = 0; k0 < KDIM; k0 += BK) {
        #pragma unroll
        for (int i = 0; i < 4; ++i) {
            const int row = srow + 32 * i;
            f32x4 av = *(const f32x4*)(xg + (size_t)(32 * i) * KDIM + k0);
            f32x4 bv = *(const f32x4*)(wg + (size_t)(32 * i) * KDIM + k0);
            s16x4 pa = { f2bf(av[0]), f2bf(av[1]), f2bf(av[2]), f2bf(av[3]) };
            s16x4 pb = { f2bf(bv[0]), f2bf(bv[1]), f2bf(bv[2]), f2bf(bv[3]) };
            *(s16x4*)&As[row * LDT + scol] = pa;
            *(s16x4*)&Bs[row * LDT + scol] = pb;
        }
        __syncthreads();
        bf16x8 af[4], bfr[4];
        #pragma unroll
        for (int mi = 0; mi < 4; ++mi)
            af[mi] = *(const bf16x8*)&As[(wr * 64 + mi * 16 + r16) * LDT + g * 8];
        #pragma unroll
        for (int ni = 0; ni < 4; ++ni)
            bfr[ni] = *(const bf16x8*)&Bs[(wc * 64 + ni * 16 + r16) * LDT + g * 8];
        #pragma unroll
        for (int mi = 0; mi < 4; ++mi)
            #pragma unroll
            for (int ni = 0; ni < 4; ++ni)
                acc[mi][ni] = __builtin_amdgcn_mfma_f32_16x16x32_bf16(
                                  af[mi], bfr[ni], acc[mi][ni], 0, 0, 0);
        __syncthreads();
    }
    float bb[4];
    #pragma unroll
    for (int ni = 0; ni < 4; ++ni)
        bb[ni] = 2.0f * Bv[tn0 + wc * 64 + ni * 16 + r16];
    #pragma unroll
    for (int mi = 0; mi < 4; ++mi)
        #pragma unroll
        for (int r = 0; r < 4; ++r) {
            const int row = tm0 + wr * 64 + mi * 16 + g * 4 + r;
            float* orow = Out + (size_t)row * NDIM + tn0 + wc * 64 + r16;
            #pragma unroll
            for (int ni = 0; ni < 4; ++ni)
                orow[ni * 16] = acc[mi][ni][r] + bb[ni];
        }
}

extern "C" void kernel_launch(void* const* d_in, const int* in_sizes, int n_in,
                              void* d_out, int out_size, void* d_ws, size_t ws_size,
                              hipStream_t stream) {
    const float* X  = (const float*)d_in[0];   // [4096, 4096]
    const float* W  = (const float*)d_in[1];   // [4096, 4096]
    const float* Bv = (const float*)d_in[2];   // [4096]
    float* Out = (float*)d_out;

    const size_t nElem = (size_t)MDIM * KDIM;          // 16.78M
    const size_t need  = 2 * nElem * sizeof(short);    // 67.1 MB

    dim3 grid(NDIM / BN, MDIM / BM);   // (32, 32)

    if (ws_size >= need) {
        short* Xb = (short*)d_ws;
        short* Wb = Xb + nElem;
        const int n8 = (int)(nElem / 8);               // 2.097M vec8 chunks
        cvt_f32_bf16<<<2048, 256, 0, stream>>>(X, Xb, n8);
        cvt_f32_bf16<<<2048, 256, 0, stream>>>(W, Wb, n8);
        gemm_bf16_gll<<<grid, 256, 0, stream>>>(Xb, Wb, Bv, Out);
    } else {
        gemm_xwt_bias2<<<grid, 256, 0, stream>>>(X, W, Bv, Out);
    }
}

// Round 3
// 141.756 us; speedup vs baseline: 1.8986x; 1.4980x over previous
//
#include <hip/hip_runtime.h>
#include <hip/hip_bf16.h>

// out = x @ W.T + 2*b ; M=N=K=4096, fp32 in/out.
// Round 3: (1) fp32->bf16 pre-convert into d_ws,
//          (2) 256x256 8-phase bf16 GEMM (m201 structure): T2 XOR-swizzled LDS
//              (conflict-free ds_read_b128), T3/T4 counted vmcnt(4) phases with
//              raw s_barrier, T5 setprio around MFMA clusters, T1 XCD swizzle.

typedef short bf16x8 __attribute__((ext_vector_type(8)));
typedef short s16x4  __attribute__((ext_vector_type(4)));
typedef short s16x8  __attribute__((ext_vector_type(8)));
typedef float f32x4  __attribute__((ext_vector_type(4)));

constexpr int MDIM = 4096, NDIM = 4096, KDIM = 4096;

typedef const __attribute__((address_space(1))) void* gas_t;
typedef __attribute__((address_space(3))) void*       las_t;

__device__ __forceinline__ short f2bf(float f) {
    __hip_bfloat16 h = __float2bfloat16(f);   // RNE
    short s; __builtin_memcpy(&s, &h, 2); return s;
}

// ---------------- pass 1: fp32 -> bf16 convert ----------------
__global__ __launch_bounds__(256)
void cvt_f32_bf16(const float* __restrict__ in, short* __restrict__ out, int n8) {
    int idx    = blockIdx.x * blockDim.x + threadIdx.x;
    int stride = gridDim.x * blockDim.x;
    const f32x4* in4 = (const f32x4*)in;
    s16x8* out8 = (s16x8*)out;
    for (int i = idx; i < n8; i += stride) {
        f32x4 a = in4[2 * i];
        f32x4 b = in4[2 * i + 1];
        s16x8 o = { f2bf(a[0]), f2bf(a[1]), f2bf(a[2]), f2bf(a[3]),
                    f2bf(b[0]), f2bf(b[1]), f2bf(b[2]), f2bf(b[3]) };
        out8[i] = o;
    }
}

// ---------------- pass 2: 256x256 8-phase bf16 GEMM ----------------
constexpr int BM = 256, BN = 256, BK = 64;
constexpr int NT  = KDIM / BK;   // 64 K-tiles
constexpr int ASZ = BM * BK;     // 16384 shorts per A buffer (32 KiB)
constexpr int BSZ = BN * BK;

// one MFMA quadrant: A-quad ds_reads + (staging via lambda) + barrier + 16 MFMA
template <int Q, class StageFn>
__device__ __forceinline__ void phase(const short* Ab, int rA, int c0, int c1,
                                      bf16x8 (&bf)[4][2], f32x4 (&acc)[8][4],
                                      StageFn&& stage) {
    bf16x8 af[2][2];
    #pragma unroll
    for (int m = 0; m < 2; ++m) {
        const short* p = &Ab[(rA + Q * 32 + m * 16) * BK];
        af[m][0] = *(const bf16x8*)(p + c0);
        af[m][1] = *(const bf16x8*)(p + c1);
    }
    stage();
    __builtin_amdgcn_s_barrier();
    __builtin_amdgcn_s_setprio(1);
    #pragma unroll
    for (int m = 0; m < 2; ++m)
        #pragma unroll
        for (int ni = 0; ni < 4; ++ni)
            #pragma unroll
            for (int kk = 0; kk < 2; ++kk)
                acc[Q * 2 + m][ni] = __builtin_amdgcn_mfma_f32_16x16x32_bf16(
                    af[m][kk], bf[ni][kk], acc[Q * 2 + m][ni], 0, 0, 0);
    __builtin_amdgcn_s_setprio(0);
}

__global__ __launch_bounds__(512, 2)
void gemm_bf16_256(const short* __restrict__ Xb, const short* __restrict__ Wb,
                   const float* __restrict__ Bv, float* __restrict__ Out)
{
    __shared__ short lds[2 * ASZ + 2 * BSZ];   // 128 KiB: A[2][256][64], B[2][256][64]

    const int tid  = threadIdx.x;
    const int lane = tid & 63;
    const int wid  = tid >> 6;          // 0..7
    const int wr   = wid >> 2;          // 0..1 (M)
    const int wc   = wid & 3;           // 0..3 (N)

    // T1: XCD-chunked block swizzle (nwg=256, 256%8==0 -> bijective)
    const int bid = blockIdx.x;
    const int lin = (bid & 7) * 32 + (bid >> 3);
    const int tm0 = (lin >> 4) * BM;
    const int tn0 = (lin & 15) * BN;

    // ---- staging geometry: linear LDS dest, inverse-swizzled global source ----
    // wave stages 2x1KB segments per half-tile; lane l -> row l>>3, granule l&7.
    // LDS granule (row, gc) must hold logical granule gc ^ (row&7).
    const int srow = lane >> 3;               // 0..7
    const int sgrn = (lane & 7) ^ srow;       // pre-swizzled source granule
    const short* aSrc[2][2];
    const short* bSrc[2][2];
    int dOff[2][2];
    #pragma unroll
    for (int h = 0; h < 2; ++h) {
        #pragma unroll
        for (int j = 0; j < 2; ++j) {
            const int r = h * 128 + (2 * wid + j) * 8;   // segment base row (mult of 8)
            aSrc[h][j] = Xb + (size_t)(tm0 + r + srow) * KDIM + sgrn * 8;
            bSrc[h][j] = Wb + (size_t)(tn0 + r + srow) * KDIM + sgrn * 8;
            dOff[h][j] = r * BK;
        }
    }
    auto stageA = [&](int kt, int h) {
        short* dst = (short*)&lds[(kt & 1) * ASZ];
        __builtin_amdgcn_global_load_lds((gas_t)(aSrc[h][0] + (size_t)kt * BK),
                                         (las_t)(dst + dOff[h][0]), 16, 0, 0);
        __builtin_amdgcn_global_load_lds((gas_t)(aSrc[h][1] + (size_t)kt * BK),
                                         (las_t)(dst + dOff[h][1]), 16, 0, 0);
    };
    auto stageB = [&](int kt, int h) {
        short* dst = (short*)&lds[2 * ASZ + (kt & 1) * BSZ];
        __builtin_amdgcn_global_load_lds((gas_t)(bSrc[h][0] + (size_t)kt * BK),
                                         (las_t)(dst + dOff[h][0]), 16, 0, 0);
        __builtin_amdgcn_global_load_lds((gas_t)(bSrc[h][1] + (size_t)kt * BK),
                                         (las_t)(dst + dOff[h][1]), 16, 0, 0);
    };

    // ---- fragment read addressing (swizzled) ----
    const int g   = lane >> 4;          // k-group 0..3 ; D-row group
    const int r16 = lane & 15;          // frag row ; D col
    const int c0  = ((0 + g) ^ (r16 & 7)) * 8;   // kk=0 granule, swizzled (elements)
    const int c1  = ((4 + g) ^ (r16 & 7)) * 8;   // kk=1
    const int rA  = wr * 128 + r16;
    const int rB  = wc * 64  + r16;

    f32x4 acc[8][4] = {};

    // ---- prologue: stage (0).B, (0).A, (1).B ; drain (0) ----
    stageB(0, 0); stageB(0, 1); stageA(0, 0); stageA(0, 1); stageB(1, 0); stageB(1, 1);
    asm volatile("s_waitcnt vmcnt(4)" ::: "memory");   // (0) complete; (1).B in flight
    __builtin_amdgcn_s_barrier();
    __builtin_amdgcn_sched_barrier(0);

    // ---- main loop: 4 phases per K-tile ----
    // ledger (steady): enter with 4 outstanding ((t+1).B); issue 8 during t;
    // vmcnt(4) at ph3 drains (t+1).A,B, keeps (t+2).B in flight across barrier.
    for (int t = 0; t < NT; ++t) {
        const short* Ab = (const short*)&lds[(t & 1) * ASZ];
        const short* Bb = (const short*)&lds[2 * ASZ + (t & 1) * BSZ];

        // phase 0: B frags (all, 8 reads) + A quad0 ; stage (t+1).A0
        bf16x8 bf[4][2];
        #pragma unroll
        for (int ni = 0; ni < 4; ++ni) {
            const short* p = &Bb[(rB + ni * 16) * BK];
            bf[ni][0] = *(const bf16x8*)(p + c0);
            bf[ni][1] = *(const bf16x8*)(p + c1);
        }
        phase<0>(Ab, rA, c0, c1, bf, acc, [&] { if (t + 1 < NT) stageA(t + 1, 0); });
        __builtin_amdgcn_s_barrier();
        // phase 1: A quad1 ; stage (t+1).A1
        phase<1>(Ab, rA, c0, c1, bf, acc, [&] { if (t + 1 < NT) stageA(t + 1, 1); });
        __builtin_amdgcn_s_barrier();
        // phase 2: A quad2 ; stage (t+2).B0
        phase<2>(Ab, rA, c0, c1, bf, acc, [&] { if (t + 2 < NT) stageB(t + 2, 0); });
        __builtin_amdgcn_s_barrier();
        // phase 3: A quad3 ; stage (t+2).B1 ; counted drain
        phase<3>(Ab, rA, c0, c1, bf, acc, [&] { if (t + 2 < NT) stageB(t + 2, 1); });
        if (t < NT - 2)       { asm volatile("s_waitcnt vmcnt(4)" ::: "memory"); }
        else if (t == NT - 2) { asm volatile("s_waitcnt vmcnt(0)" ::: "memory"); }
        __builtin_amdgcn_s_barrier();
        __builtin_amdgcn_sched_barrier(0);   // pin next tile's ds_reads after this point
    }

    // ---- epilogue: + 2*bias, fp32 store ----
    float bb[4];
    #pragma unroll
    for (int ni = 0; ni < 4; ++ni)
        bb[ni] = 2.0f * Bv[tn0 + wc * 64 + ni * 16 + r16];

    #pragma unroll
    for (int mi = 0; mi < 8; ++mi) {
        #pragma unroll
        for (int r = 0; r < 4; ++r) {
            const int row = tm0 + wr * 128 + mi * 16 + g * 4 + r;
            float* orow = Out + (size_t)row * NDIM + tn0 + wc * 64 + r16;
            #pragma unroll
            for (int ni = 0; ni < 4; ++ni)
                orow[ni * 16] = acc[mi][ni][r] + bb[ni];
        }
    }
}

// ---------------- fallback: fp32 reg-staged (R1, if ws too small) ----------------
constexpr int FBM = 128, FBN = 128, FBK = 32, LDT = FBK + 8;
__global__ __launch_bounds__(256)
void gemm_xwt_bias2(const float* __restrict__ X, const float* __restrict__ W,
                    const float* __restrict__ Bv, float* __restrict__ Out)
{
    __shared__ short As[FBM * LDT];
    __shared__ short Bs[FBN * LDT];
    const int tid  = threadIdx.x;
    const int lane = tid & 63;
    const int wid  = tid >> 6;
    const int wr   = wid >> 1;
    const int wc   = wid & 1;
    const int tm0  = blockIdx.y * FBM;
    const int tn0  = blockIdx.x * FBN;
    const int srow = tid >> 3;
    const int scol = (tid & 7) * 4;
    const int g    = lane >> 4;
    const int r16  = lane & 15;
    f32x4 acc[4][4] = {};
    const float* xg = X + (size_t)(tm0 + srow) * KDIM + scol;
    const float* wg = W + (size_t)(tn0 + srow) * KDIM + scol;
    for (int k0 = 0; k0 < KDIM; k0 += FBK) {
        #pragma unroll
        for (int i = 0; i < 4; ++i) {
            const int row = srow + 32 * i;
            f32x4 av = *(const f32x4*)(xg + (size_t)(32 * i) * KDIM + k0);
            f32x4 bv = *(const f32x4*)(wg + (size_t)(32 * i) * KDIM + k0);
            s16x4 pa = { f2bf(av[0]), f2bf(av[1]), f2bf(av[2]), f2bf(av[3]) };
            s16x4 pb = { f2bf(bv[0]), f2bf(bv[1]), f2bf(bv[2]), f2bf(bv[3]) };
            *(s16x4*)&As[row * LDT + scol] = pa;
            *(s16x4*)&Bs[row * LDT + scol] = pb;
        }
        __syncthreads();
        bf16x8 af[4], bfr[4];
        #pragma unroll
        for (int mi = 0; mi < 4; ++mi)
            af[mi] = *(const bf16x8*)&As[(wr * 64 + mi * 16 + r16) * LDT + g * 8];
        #pragma unroll
        for (int ni = 0; ni < 4; ++ni)
            bfr[ni] = *(const bf16x8*)&Bs[(wc * 64 + ni * 16 + r16) * LDT + g * 8];
        #pragma unroll
        for (int mi = 0; mi < 4; ++mi)
            #pragma unroll
            for (int ni = 0; ni < 4; ++ni)
                acc[mi][ni] = __builtin_amdgcn_mfma_f32_16x16x32_bf16(
                                  af[mi], bfr[ni], acc[mi][ni], 0, 0, 0);
        __syncthreads();
    }
    float bb[4];
    #pragma unroll
    for (int ni = 0; ni < 4; ++ni)
        bb[ni] = 2.0f * Bv[tn0 + wc * 64 + ni * 16 + r16];
    #pragma unroll
    for (int mi = 0; mi < 4; ++mi)
        #pragma unroll
        for (int r = 0; r < 4; ++r) {
            const int row = tm0 + wr * 64 + mi * 16 + g * 4 + r;
            float* orow = Out + (size_t)row * NDIM + tn0 + wc * 64 + r16;
            #pragma unroll
            for (int ni = 0; ni < 4; ++ni)
                orow[ni * 16] = acc[mi][ni][r] + bb[ni];
        }
}

extern "C" void kernel_launch(void* const* d_in, const int* in_sizes, int n_in,
                              void* d_out, int out_size, void* d_ws, size_t ws_size,
                              hipStream_t stream) {
    const float* X  = (const float*)d_in[0];
    const float* W  = (const float*)d_in[1];
    const float* Bv = (const float*)d_in[2];
    float* Out = (float*)d_out;

    const size_t nElem = (size_t)MDIM * KDIM;
    const size_t need  = 2 * nElem * sizeof(short);   // 67.1 MB

    if (ws_size >= need) {
        short* Xb = (short*)d_ws;
        short* Wb = Xb + nElem;
        const int n8 = (int)(nElem / 8);
        cvt_f32_bf16<<<2048, 256, 0, stream>>>(X, Xb, n8);
        cvt_f32_bf16<<<2048, 256, 0, stream>>>(W, Wb, n8);
        gemm_bf16_256<<<dim3(256), 512, 0, stream>>>(Xb, Wb, Bv, Out);
    } else {
        dim3 grid(NDIM / FBN, MDIM / FBM);
        gemm_xwt_bias2<<<grid, 256, 0, stream>>>(X, W, Bv, Out);
    }
}